// Round 19
// baseline (250.104 us; speedup 1.0000x reference)
//
#include <hip/hip_runtime.h>
#include <math.h>

typedef __attribute__((ext_vector_type(8))) short short8;
typedef __attribute__((ext_vector_type(4))) short short4v;
typedef __attribute__((ext_vector_type(4))) float f32x4;
typedef unsigned short ushort;
typedef unsigned int uint;
typedef unsigned long long u64;

#define MFMA16(a, b, c) __builtin_amdgcn_mfma_f32_16x16x32_bf16(a, b, c, 0, 0, 0)
#define NBLK 256
#define SBAR() __builtin_amdgcn_sched_barrier(0)

__device__ __forceinline__ ushort f2bf(float f) {
  uint u = __float_as_uint(f);
  u = (u + 0x7FFFu + ((u >> 16) & 1u)) >> 16;
  return (ushort)u;
}
__device__ __forceinline__ int swz(int idx, int sh) {
  return idx ^ (((idx >> sh) & 7) << 3);
}
__device__ __forceinline__ float wsum(float v) {
#pragma unroll
  for (int off = 32; off > 0; off >>= 1) v += __shfl_xor(v, off, 64);
  return v;
}
// weights: normal cached load (L2-resident after the one-time post-cvt inv)
__device__ __forceinline__ void gload16(short8& dst, const ushort* g) {
  asm volatile("global_load_dwordx4 %0, %1, off" : "=v"(dst) : "v"((u64)g));
}
// activations / ws-writes: system-coherent (bypass non-coherent per-XCD L2)
__device__ __forceinline__ void ld16cc(short8& d, const void* g) {
  asm volatile("global_load_dwordx4 %0, %1, off sc0 sc1" : "=v"(d) : "v"((u64)g));
}
__device__ __forceinline__ void ldf4cc(f32x4& d, const void* g) {
  asm volatile("global_load_dwordx4 %0, %1, off sc0 sc1" : "=v"(d) : "v"((u64)g));
}
__device__ __forceinline__ void st16cc(void* g, short8 v) {
  asm volatile("global_store_dwordx4 %0, %1, off sc0 sc1" ::"v"((u64)g), "v"(v)
               : "memory");
}
__device__ __forceinline__ void stf4cc(void* g, f32x4 v) {
  asm volatile("global_store_dwordx4 %0, %1, off sc0 sc1" ::"v"((u64)g), "v"(v)
               : "memory");
}
__device__ __forceinline__ void stf1cc(void* g, float v) {
  asm volatile("global_store_dword %0, %1, off sc0 sc1" ::"v"((u64)g), "v"(v)
               : "memory");
}
__device__ __forceinline__ void stu2cc(void* g, ushort v) {
  asm volatile("global_store_short %0, %1, off sc0 sc1" ::"v"((u64)g),
               "v"((uint)v)
               : "memory");
}
__device__ __forceinline__ void vmw(int n) {
  if (n >= 11) asm volatile("s_waitcnt vmcnt(11)" ::: "memory");
  else if (n == 10) asm volatile("s_waitcnt vmcnt(10)" ::: "memory");
  else if (n == 9) asm volatile("s_waitcnt vmcnt(9)" ::: "memory");
  else if (n == 8) asm volatile("s_waitcnt vmcnt(8)" ::: "memory");
  else if (n == 7) asm volatile("s_waitcnt vmcnt(7)" ::: "memory");
  else if (n == 6) asm volatile("s_waitcnt vmcnt(6)" ::: "memory");
  else if (n == 5) asm volatile("s_waitcnt vmcnt(5)" ::: "memory");
  else if (n == 4) asm volatile("s_waitcnt vmcnt(4)" ::: "memory");
  else if (n == 3) asm volatile("s_waitcnt vmcnt(3)" ::: "memory");
  else if (n == 2) asm volatile("s_waitcnt vmcnt(2)" ::: "memory");
  else if (n == 1) asm volatile("s_waitcnt vmcnt(1)" ::: "memory");
  else asm volatile("s_waitcnt vmcnt(0)" ::: "memory");
}

// two-level tree barrier: 8 group counters (32 blocks each) + root.
// Serialization per barrier: 32 adds/group-line (parallel across 8 lines)
// + 8 root adds, vs R18's 256 adds on ONE line (~13us/barrier).
// base = cnt + bi*16: [0..7] group counters, [8] root.
__device__ __forceinline__ void gbar(uint* base, int tid, int bid) {
  asm volatile("s_waitcnt vmcnt(0) lgkmcnt(0)" ::: "memory");
  __syncthreads();
  if (tid == 0) {
    uint old = __hip_atomic_fetch_add(base + (bid >> 5), 1u, __ATOMIC_RELAXED,
                                      __HIP_MEMORY_SCOPE_AGENT);
    if (old == 31)
      __hip_atomic_fetch_add(base + 8, 1u, __ATOMIC_RELAXED,
                             __HIP_MEMORY_SCOPE_AGENT);
    while (__hip_atomic_load(base + 8, __ATOMIC_RELAXED,
                             __HIP_MEMORY_SCOPE_AGENT) < 8u)
      __builtin_amdgcn_s_sleep(2);
  }
  __syncthreads();
}

// ---- weight stream layout (tile-major): chunk(1KB) = (tile, kc, ks) ------
#define S_CONV2 0
#define S_TREND 196608
#define S_SEASON 262144
#define S_QKV 327680
#define S_AOW 1114112
#define S_F1 1376256
#define S_F2 2424832
#define WTOT 3473408
#define O_BAR 3473408
#define O_C2O 3653632
#define O_G0 3981312
#define O_G1 4308992
#define O_PEND 4636672
#define O_QKV 4964352
#define O_FFB 5455872

struct P {
  const float *x, *c1w, *c1b, *c2w, *c2b, *lnfg, *lnfb, *tw, *tb, *sw, *sb;
  const float *aiw, *aib, *aow, *aobb, *l1g, *l1b, *f1w, *f1b, *f2w, *f2b;
  const float *l2g, *l2b, *fcw, *fcb;
  ushort* ws;
  float* out;
  float *c2o, *g0, *g1, *pend;
  ushort *qkvo, *ffbo;
};

template <int NCH>
__device__ __forceinline__ void dec2(int idx, int& row, int& k) {
  int pos = idx & 511, lane = pos >> 3, j = pos & 7;
  int kg = lane >> 4, col = lane & 15;
  int chunk = idx >> 9;
  int tile = chunk / (NCH * 4), r = chunk - tile * (NCH * 4);
  int kc = r >> 2, ks = r & 3;
  row = tile * 16 + col;
  k = kc * 128 + ks * 32 + kg * 8 + j;
}

// ---- ring GEMM (register ring, counted vmcnt) ----------------------------
template <int R, int C>
__device__ __forceinline__ void ring_pro(const ushort* ws0, short8* rg) {
#pragma unroll
  for (int r = 0; r < R; ++r) gload16(rg[r], ws0 + r * 512);
}

template <int NCH, int MY, int ASH, int R>
__device__ __forceinline__ void ring_consume(const ushort* __restrict__ A,
                                             int lda,
                                             const ushort* __restrict__ ws0,
                                             short8* rg, int lane,
                                             f32x4 (&acc)[MY][2]) {
  constexpr int C = MY * NCH * 4;
  const int col = lane & 15, kg = lane >> 4;
  const int r1c = (16 + col > 19) ? 19 : (16 + col);
  short8 af0[4], af1[4];
#pragma unroll
  for (int c = 0; c < C; ++c) {
    const int i = c / (NCH * 4), r = c - i * (NCH * 4);
    const int kc = r >> 2, ks = r & 3;
    if (ks == 0) {
#pragma unroll
      for (int s = 0; s < 4; ++s) {
        const int k0 = kc * 128 + s * 32 + kg * 8;
        af0[s] = *(const short8*)(A + swz(col * lda + k0, ASH));
        af1[s] = *(const short8*)(A + swz(r1c * lda + k0, ASH));
      }
    }
    int allow = C - 1 - c; if (allow > R - 1) allow = R - 1;
    vmw(allow);
    SBAR();
    acc[i][0] = MFMA16(af0[ks], rg[c % R], acc[i][0]);
    acc[i][1] = MFMA16(af1[ks], rg[c % R], acc[i][1]);
    if (c + R < C) gload16(rg[c % R], ws0 + (c + R) * 512);
  }
}

// ---- cc staging helpers (issue-all -> one wait -> SBAR -> consume) -------
template <int N, int SH>
__device__ __forceinline__ void stage_b16cc(const ushort* g, ushort* hb,
                                            int tid) {
  constexpr int T = (N + 2047) / 2048;
  short8 v[T];
#pragma unroll
  for (int t = 0; t < T; ++t) {
    int i = tid * 8 + t * 2048;
    if (i < N) ld16cc(v[t], g + i);
  }
  vmw(0);
  SBAR();
#pragma unroll
  for (int t = 0; t < T; ++t) {
    int i = tid * 8 + t * 2048;
    if (i < N) *(short8*)(hb + swz(i, SH)) = v[t];
  }
}
__device__ __forceinline__ void stage_f32cc(const float* g, ushort* hb,
                                            int tid) {
  f32x4 a[3], b[3];
#pragma unroll
  for (int t = 0; t < 3; ++t) {
    int i = tid * 8 + t * 2048;
    if (i < 5120) { ldf4cc(a[t], g + i); ldf4cc(b[t], g + i + 4); }
  }
  vmw(0);
  SBAR();
#pragma unroll
  for (int t = 0; t < 3; ++t) {
    int i = tid * 8 + t * 2048;
    if (i < 5120) {
      short8 o;
      o[0] = f2bf(a[t][0]); o[1] = f2bf(a[t][1]);
      o[2] = f2bf(a[t][2]); o[3] = f2bf(a[t][3]);
      o[4] = f2bf(b[t][0]); o[5] = f2bf(b[t][1]);
      o[6] = f2bf(b[t][2]); o[7] = f2bf(b[t][3]);
      *(short8*)(hb + swz(i, 8)) = o;
    }
  }
}
__device__ __forceinline__ void stage_lncc(const float* g1, const float* pend,
                                           const float* gam, const float* bet,
                                           ushort* hb, float* gout,
                                           float* f32lds, int tid) {
  const int lane = tid & 63, w = tid >> 6, d0 = lane * 4;
  f32x4 av[5], pv[5];
#pragma unroll
  for (int t = 0; t < 5; ++t) {
    int r = w + t * 4;
    ldf4cc(av[t], g1 + r * 256 + d0);
    if (pend) ldf4cc(pv[t], pend + r * 256 + d0);
  }
  vmw(0);
  SBAR();
#pragma unroll
  for (int t = 0; t < 5; ++t) {
    int r = w + t * 4;
    f32x4 a = av[t];
    if (pend) a += pv[t];
    float m = wsum(a[0] + a[1] + a[2] + a[3]) * (1.f / 256.f);
    f32x4 cv = a - m;
    float var = wsum(cv[0] * cv[0] + cv[1] * cv[1] + cv[2] * cv[2] +
                     cv[3] * cv[3]) * (1.f / 256.f);
    float inv = rsqrtf(var + 1e-5f);
    f32x4 o;
    o[0] = cv[0] * inv * gam[d0] + bet[d0];
    o[1] = cv[1] * inv * gam[d0 + 1] + bet[d0 + 1];
    o[2] = cv[2] * inv * gam[d0 + 2] + bet[d0 + 2];
    o[3] = cv[3] * inv * gam[d0 + 3] + bet[d0 + 3];
    short4v tt;
    tt[0] = f2bf(o[0]); tt[1] = f2bf(o[1]); tt[2] = f2bf(o[2]); tt[3] = f2bf(o[3]);
    *(short4v*)(hb + swz(r * 256 + d0, 8)) = tt;
    if (gout) stf4cc(gout + r * 256 + d0, o);
    if (f32lds) *(f32x4*)(f32lds + r * 256 + d0) = o;
  }
}

// ---- phase bodies --------------------------------------------------------
__device__ void ph_cvt(const P& p, int gtid) {
  for (int base = gtid * 8; base < WTOT; base += NBLK * 256 * 8) {
    short8 o;
#pragma unroll
    for (int j = 0; j < 8; ++j) {
      int i = base + j;
      float v; int row, k;
      if (i < S_TREND) {
        dec2<6>(i, row, k);
        int t = k >> 8, e = k & 255;
        v = p.c2w[row * 768 + e * 3 + t];
      } else if (i < S_SEASON) { dec2<2>(i - S_TREND, row, k); v = p.tw[row * 256 + k]; }
      else if (i < S_QKV) { dec2<2>(i - S_SEASON, row, k); v = p.sw[row * 256 + k]; }
      else if (i < S_AOW) {
        int r = i - S_QKV; int l = r / 196608; r -= l * 196608;
        dec2<2>(r, row, k); v = p.aiw[(size_t)l * 196608 + row * 256 + k];
      } else if (i < S_F1) {
        int r = i - S_AOW; int l = r >> 16; r &= 65535;
        dec2<2>(r, row, k); v = p.aow[l * 65536 + row * 256 + k];
      } else if (i < S_F2) {
        int r = i - S_F1; int l = r >> 18; r &= 262143;
        dec2<2>(r, row, k); v = p.f1w[l * 262144 + row * 256 + k];
      } else {
        int r = i - S_F2; int l = r >> 18; r &= 262143;
        dec2<8>(r, row, k); v = p.f2w[l * 262144 + row * 1024 + k];
      }
      o[j] = (short)f2bf(v);
    }
    st16cc(p.ws + base, o);
  }
}

__device__ void ph_conv12(const P& p, ushort* SM, int unit, int tid) {
  float* xs = (float*)SM;
  ushort* c1u = SM + 768;
  const int lane = tid & 63, wv = tid >> 6;
  const int b = unit >> 2, slice = unit & 3;
  const int col = lane & 15, kg = lane >> 4;
  const int tile = slice * 4 + wv, og = tile * 16 + col;
  const ushort* ws0 = p.ws + S_CONV2 + tile * 12288 + lane * 8;
  short8 rg[12];
  ring_pro<12, 24>(ws0, rg);
  for (int i = tid; i < 24 * 16; i += 256) {
    int r = i >> 4, c = i & 15;
    xs[r * 16 + c] = (r < 23) ? p.x[((size_t)b * 4000 + 3977 + r) * 16 + c] : 0.f;
  }
  __syncthreads();
  {
    const int d = tid;
    const float* wr = p.c1w + d * 48;
    float acc[21];
    const float bv = p.c1b[d];
#pragma unroll
    for (int r = 0; r < 21; ++r) acc[r] = bv;
    for (int c = 0; c < 16; ++c) {
      float xv[23];
#pragma unroll
      for (int i = 0; i < 23; ++i) xv[i] = xs[(i + 1) * 16 + c];
      float w0 = wr[c * 3], w1 = wr[c * 3 + 1], w2 = wr[c * 3 + 2];
#pragma unroll
      for (int r = 0; r < 21; ++r)
        acc[r] += xv[r] * w0 + xv[r + 1] * w1 + xv[r + 2] * w2;
    }
#pragma unroll
    for (int r = 0; r < 21; ++r)
      c1u[swz(r * 256 + d, 8)] = f2bf(fmaxf(acc[r], 0.f));
    c1u[swz(21 * 256 + d, 8)] = 0;
  }
  float bv2 = p.c2b[og];
  __syncthreads();
  f32x4 acc2[1][2];
  acc2[0][0] = {bv2, bv2, bv2, bv2}; acc2[0][1] = {bv2, bv2, bv2, bv2};
  ring_consume<6, 1, 8, 12>(c1u, 256, ws0, rg, lane, acc2);
  float* ob = p.c2o + b * 5120;
#pragma unroll
  for (int mt = 0; mt < 2; ++mt)
#pragma unroll
    for (int j = 0; j < 4; ++j) {
      int row = mt * 16 + kg * 4 + j;
      if (row < 20) stf1cc(ob + row * 256 + og, fmaxf(acc2[0][mt][j], 0.f));
    }
}

__device__ void ph_tresea(const P& p, ushort* SM, int unit, int tid) {
  ushort* hb = SM;
  float* hf = (float*)(SM + 5120);
  const int lane = tid & 63, wv = tid >> 6;
  const int b = unit >> 2, slice = unit & 3;
  const int col = lane & 15, kg = lane >> 4;
  const int tile = slice * 4 + wv, og = tile * 16 + col;
  const ushort* wt0 = p.ws + S_TREND + tile * 4096 + lane * 8;
  const ushort* ws0 = p.ws + S_SEASON + tile * 4096 + lane * 8;
  short8 rgt[8], rgs[8];
  ring_pro<8, 8>(wt0, rgt);
  ring_pro<8, 8>(ws0, rgs);
  stage_lncc(p.c2o + b * 5120, nullptr, p.lnfg, p.lnfb, hb, nullptr, hf, tid);
  float bt = p.tb[og], bs = p.sb[og];
  __syncthreads();
  f32x4 at[1][2], as_[1][2];
  at[0][0] = {bt, bt, bt, bt}; at[0][1] = {bt, bt, bt, bt};
  as_[0][0] = {bs, bs, bs, bs}; as_[0][1] = {bs, bs, bs, bs};
  ring_consume<2, 1, 8, 8>(hb, 256, wt0, rgt, lane, at);
  ring_consume<2, 1, 8, 8>(hb, 256, ws0, rgs, lane, as_);
  float* ob = p.g0 + b * 5120;
#pragma unroll
  for (int mt = 0; mt < 2; ++mt)
#pragma unroll
    for (int j = 0; j < 4; ++j) {
      int row = mt * 16 + kg * 4 + j;
      if (row < 20)
        stf1cc(ob + row * 256 + og,
               hf[row * 256 + og] + at[0][mt][j] + sinf(as_[0][mt][j]));
    }
}

// qkv single-pass: 192 blocks, 6 slices/batch, MY=2 (tiles slice*8+wv*2+i)
__device__ void ph_qkv(const P& p, ushort* SM, int unit, int tid, int l) {
  ushort* hb = SM;
  const int lane = tid & 63, wv = tid >> 6;
  const int b = unit / 6, slice = unit % 6;
  const int col = lane & 15, kg = lane >> 4;
  const int t0 = slice * 8 + wv * 2;
  const ushort* ws0 = p.ws + S_QKV + l * 196608 + t0 * 4096 + lane * 8;
  short8 rg[8];
  ring_pro<8, 16>(ws0, rg);
  if (l)
    stage_lncc(p.g1 + b * 5120, p.pend + b * 5120, p.l2g + (l - 1) * 256,
               p.l2b + (l - 1) * 256, hb,
               (slice == 0) ? (p.g0 + b * 5120) : nullptr, nullptr, tid);
  else
    stage_f32cc(p.g0 + b * 5120, hb, tid);
  float bv0 = p.aib[l * 768 + t0 * 16 + col];
  float bv1 = p.aib[l * 768 + (t0 + 1) * 16 + col];
  __syncthreads();
  f32x4 acc[2][2];
  acc[0][0] = {bv0, bv0, bv0, bv0}; acc[0][1] = {bv0, bv0, bv0, bv0};
  acc[1][0] = {bv1, bv1, bv1, bv1}; acc[1][1] = {bv1, bv1, bv1, bv1};
  ring_consume<2, 2, 8, 8>(hb, 256, ws0, rg, lane, acc);
  ushort* ob = p.qkvo + b * 15360;
#pragma unroll
  for (int i = 0; i < 2; ++i) {
    const int og = (t0 + i) * 16 + col;
#pragma unroll
    for (int mt = 0; mt < 2; ++mt)
#pragma unroll
      for (int j = 0; j < 4; ++j) {
        int row = mt * 16 + kg * 4 + j;
        if (row < 20) stu2cc(ob + row * 768 + og, f2bf(acc[i][mt][j]));
      }
  }
}

__device__ void ph_aff1(const P& p, ushort* SM, int unit, int tid, int l) {
  ushort* qb = SM;
  ushort* vT = SM + 15360;
  ushort* Pb = SM + 23552;
  ushort* aob = SM + 28672;
  ushort* hb = SM + 33792;
  float* sc = (float*)(SM + 38912);
  float* proj = (float*)qb;
  const int lane = tid & 63, wv = tid >> 6;
  const int b = unit >> 3, slice = unit & 7;
  const int col = lane & 15, kg = lane >> 4;
  const int r1c = (16 + col > 19) ? 19 : (16 + col);

  const ushort* wo0 = p.ws + S_AOW + l * 65536 + (wv * 4) * 4096 + lane * 8;
  short8 rgo[12];
  ring_pro<12, 32>(wo0, rgo);
  const int t0 = slice * 8 + wv * 2;
  const ushort* wf0 = p.ws + S_F1 + l * 262144 + t0 * 4096 + lane * 8;
  short8 rgf[8];
  ring_pro<8, 8>(wf0, rgf);

  stage_b16cc<15360, 8>(p.qkvo + b * 15360, qb, tid);
  __syncthreads();
  for (int i = tid; i < 8192; i += 256) {
    int hh = i >> 10, rem = i & 1023, dh = rem >> 5, tk = rem & 31;
    ushort v = (tk < 20) ? qb[swz(tk * 768 + 512 + hh * 32 + dh, 8)] : (ushort)0;
    vT[swz(i, 5)] = v;
  }
  __syncthreads();
  for (int hh = wv; hh < 8; hh += 4) {
    short8 aq[2], bk[2];
    aq[0] = *(const short8*)(qb + swz(col * 768 + hh * 32 + kg * 8, 8));
    aq[1] = *(const short8*)(qb + swz(r1c * 768 + hh * 32 + kg * 8, 8));
    bk[0] = *(const short8*)(qb + swz(col * 768 + 256 + hh * 32 + kg * 8, 8));
    bk[1] = *(const short8*)(qb + swz(r1c * 768 + 256 + hh * 32 + kg * 8, 8));
    f32x4 d[2][2];
#pragma unroll
    for (int mt = 0; mt < 2; ++mt)
#pragma unroll
      for (int nt = 0; nt < 2; ++nt) {
        d[mt][nt] = {0.f, 0.f, 0.f, 0.f};
        d[mt][nt] = MFMA16(aq[mt], bk[nt], d[mt][nt]);
      }
#pragma unroll
    for (int mt = 0; mt < 2; ++mt)
#pragma unroll
      for (int nt = 0; nt < 2; ++nt)
#pragma unroll
        for (int j = 0; j < 4; ++j) {
          int row = mt * 16 + kg * 4 + j, kj = nt * 16 + col;
          if (row < 20 && kj < 20)
            sc[hh * 400 + row * 20 + kj] = d[mt][nt][j] * 0.17677669529663687f;
        }
  }
  __syncthreads();
  if (tid < 160) {
    const int hh = tid / 20, q = tid - hh * 20;
    const float* row = sc + hh * 400 + q * 20;
    float m = row[0];
#pragma unroll
    for (int j = 1; j < 20; ++j) m = fmaxf(m, row[j]);
    float e[20], s = 0.f;
#pragma unroll
    for (int j = 0; j < 20; ++j) { e[j] = __expf(row[j] - m); s += e[j]; }
    float inv = 1.f / s;
#pragma unroll
    for (int j = 0; j < 20; ++j) Pb[swz(hh * 640 + q * 32 + j, 5)] = f2bf(e[j] * inv);
#pragma unroll
    for (int j = 20; j < 32; ++j) Pb[swz(hh * 640 + q * 32 + j, 5)] = 0;
  }
  __syncthreads();
  for (int hh = wv; hh < 8; hh += 4) {
    short8 ap[2], bvv[2];
    ap[0] = *(const short8*)(Pb + swz(hh * 640 + col * 32 + kg * 8, 5));
    ap[1] = *(const short8*)(Pb + swz(hh * 640 + r1c * 32 + kg * 8, 5));
    bvv[0] = *(const short8*)(vT + swz(hh * 1024 + col * 32 + kg * 8, 5));
    bvv[1] = *(const short8*)(vT + swz(hh * 1024 + (16 + col) * 32 + kg * 8, 5));
    f32x4 d[2][2];
#pragma unroll
    for (int mt = 0; mt < 2; ++mt)
#pragma unroll
      for (int nt = 0; nt < 2; ++nt) {
        d[mt][nt] = {0.f, 0.f, 0.f, 0.f};
        d[mt][nt] = MFMA16(ap[mt], bvv[nt], d[mt][nt]);
      }
#pragma unroll
    for (int mt = 0; mt < 2; ++mt)
#pragma unroll
      for (int nt = 0; nt < 2; ++nt)
#pragma unroll
        for (int j = 0; j < 4; ++j) {
          int row = mt * 16 + kg * 4 + j, dc = nt * 16 + col;
          if (row < 20) aob[swz(row * 256 + hh * 32 + dc, 8)] = f2bf(d[mt][nt][j]);
        }
  }
  __syncthreads();

  {
    float bo[4];
#pragma unroll
    for (int i = 0; i < 4; ++i) bo[i] = p.aobb[l * 256 + (wv * 4 + i) * 16 + col];
    f32x4 acc[4][2];
#pragma unroll
    for (int i = 0; i < 4; ++i) {
      acc[i][0] = {bo[i], bo[i], bo[i], bo[i]};
      acc[i][1] = {bo[i], bo[i], bo[i], bo[i]};
    }
    ring_consume<2, 4, 8, 12>(aob, 256, wo0, rgo, lane, acc);
#pragma unroll
    for (int i = 0; i < 4; ++i) {
      const int og = (wv * 4 + i) * 16 + col;
#pragma unroll
      for (int mt = 0; mt < 2; ++mt)
#pragma unroll
        for (int j = 0; j < 4; ++j) {
          int row = mt * 16 + kg * 4 + j;
          if (row < 20) proj[row * 256 + og] = acc[i][mt][j];
        }
    }
  }
  __syncthreads();

  // LN1(g0 + proj) -> hb bf16 (slice0 cc-writes g1)
  {
    const int d0 = lane * 4;
    const float* l1gp = p.l1g + l * 256;
    const float* l1bp = p.l1b + l * 256;
    f32x4 gv[5];
#pragma unroll
    for (int t = 0; t < 5; ++t) {
      int r = wv + t * 4;
      ldf4cc(gv[t], p.g0 + b * 5120 + r * 256 + d0);
    }
    vmw(0);
    SBAR();
#pragma unroll
    for (int t = 0; t < 5; ++t) {
      int r = wv + t * 4;
      f32x4 a = gv[t];
      a[0] += proj[r * 256 + d0];
      a[1] += proj[r * 256 + d0 + 1];
      a[2] += proj[r * 256 + d0 + 2];
      a[3] += proj[r * 256 + d0 + 3];
      float m = wsum(a[0] + a[1] + a[2] + a[3]) * (1.f / 256.f);
      f32x4 cv = a - m;
      float var = wsum(cv[0] * cv[0] + cv[1] * cv[1] + cv[2] * cv[2] +
                       cv[3] * cv[3]) * (1.f / 256.f);
      float inv = rsqrtf(var + 1e-5f);
      f32x4 o;
      o[0] = cv[0] * inv * l1gp[d0] + l1bp[d0];
      o[1] = cv[1] * inv * l1gp[d0 + 1] + l1bp[d0 + 1];
      o[2] = cv[2] * inv * l1gp[d0 + 2] + l1bp[d0 + 2];
      o[3] = cv[3] * inv * l1gp[d0 + 3] + l1bp[d0 + 3];
      short4v tt;
      tt[0] = f2bf(o[0]); tt[1] = f2bf(o[1]); tt[2] = f2bf(o[2]); tt[3] = f2bf(o[3]);
      *(short4v*)(hb + swz(r * 256 + d0, 8)) = tt;
      if (slice == 0) stf4cc(p.g1 + b * 5120 + r * 256 + d0, o);
    }
  }
  __syncthreads();

  {
    float bf0 = p.f1b[l * 1024 + t0 * 16 + col];
    float bf1 = p.f1b[l * 1024 + (t0 + 1) * 16 + col];
    f32x4 acc[2][2];
    acc[0][0] = {bf0, bf0, bf0, bf0}; acc[0][1] = {bf0, bf0, bf0, bf0};
    acc[1][0] = {bf1, bf1, bf1, bf1}; acc[1][1] = {bf1, bf1, bf1, bf1};
    ring_consume<2, 2, 8, 8>(hb, 256, wf0, rgf, lane, acc);
    ushort* ob = p.ffbo + b * 20480;
#pragma unroll
    for (int i = 0; i < 2; ++i) {
      const int og = (t0 + i) * 16 + col;
#pragma unroll
      for (int mt = 0; mt < 2; ++mt)
#pragma unroll
        for (int j = 0; j < 4; ++j) {
          int row = mt * 16 + kg * 4 + j;
          if (row < 20)
            stu2cc(ob + row * 1024 + og, f2bf(fmaxf(acc[i][mt][j], 0.f)));
        }
    }
  }
}

__device__ void ph_ff2(const P& p, ushort* SM, int unit, int tid, int l) {
  ushort* hb = SM;
  const int lane = tid & 63, wv = tid >> 6;
  const int b = unit >> 2, slice = unit & 3;
  const int col = lane & 15, kg = lane >> 4;
  const int tile = slice * 4 + wv, og = tile * 16 + col;
  const ushort* ws0 = p.ws + S_F2 + l * 262144 + tile * 16384 + lane * 8;
  short8 rg[12];
  ring_pro<12, 32>(ws0, rg);
  stage_b16cc<20480, 10>(p.ffbo + b * 20480, hb, tid);
  float bv = p.f2b[l * 256 + og];
  __syncthreads();
  f32x4 acc[1][2];
  acc[0][0] = {bv, bv, bv, bv}; acc[0][1] = {bv, bv, bv, bv};
  ring_consume<8, 1, 10, 12>(hb, 1024, ws0, rg, lane, acc);
  float* ob = p.pend + b * 5120;
#pragma unroll
  for (int mt = 0; mt < 2; ++mt)
#pragma unroll
    for (int j = 0; j < 4; ++j) {
      int row = mt * 16 + kg * 4 + j;
      if (row < 20) stf1cc(ob + row * 256 + og, acc[0][mt][j]);
    }
}

__device__ void ph_fc(const P& p, ushort* SM, int b, int tid) {
  float* hn = (float*)SM;
  if (tid < 64) {
    const int d0 = tid * 4;
    const float* lng = p.l2g + 3 * 256;
    const float* lnb = p.l2b + 3 * 256;
    f32x4 a, q;
    ldf4cc(a, p.g1 + b * 5120 + 19 * 256 + d0);
    ldf4cc(q, p.pend + b * 5120 + 19 * 256 + d0);
    vmw(0);
    SBAR();
    a += q;
    float m = wsum(a[0] + a[1] + a[2] + a[3]) * (1.f / 256.f);
    f32x4 cv = a - m;
    float var = wsum(cv[0] * cv[0] + cv[1] * cv[1] + cv[2] * cv[2] +
                     cv[3] * cv[3]) * (1.f / 256.f);
    float inv = rsqrtf(var + 1e-5f);
    hn[d0] = cv[0] * inv * lng[d0] + lnb[d0];
    hn[d0 + 1] = cv[1] * inv * lng[d0 + 1] + lnb[d0 + 1];
    hn[d0 + 2] = cv[2] * inv * lng[d0 + 2] + lnb[d0 + 2];
    hn[d0 + 3] = cv[3] * inv * lng[d0 + 3] + lnb[d0 + 3];
  }
  __syncthreads();
  const int g = tid >> 4, t = tid & 15;
  float s = 0.f;
#pragma unroll
  for (int j = 0; j < 16; ++j) {
    int k = t * 16 + j;
    s += hn[k] * p.fcw[g * 256 + k];
  }
#pragma unroll
  for (int off = 1; off < 16; off <<= 1) s += __shfl_xor(s, off, 64);
  if (t == 0) p.out[b * 16 + g] = s + p.fcb[g];
}

// ---- the mega kernel -----------------------------------------------------
__global__ __launch_bounds__(256, 1) void mega(P p) {
  __shared__ __align__(16) ushort SM[45440];
  const int tid = threadIdx.x, bid = blockIdx.x;
  uint* cnt = (uint*)(p.ws + O_BAR);
  int bi = 0;

  ph_cvt(p, bid * 256 + tid);
  gbar(cnt + 16 * bi++, tid, bid);
  // ONE-TIME L2 writeback+invalidate: discard stale ws lines so normal-cached
  // weight reads see the sc-written data. ws is never written again.
  __threadfence();

  if (bid < 128) ph_conv12(p, SM, bid, tid);
  gbar(cnt + 16 * bi++, tid, bid);

  if (bid < 128) ph_tresea(p, SM, bid, tid);
  gbar(cnt + 16 * bi++, tid, bid);

  for (int l = 0; l < 4; ++l) {
    if (bid < 192) ph_qkv(p, SM, bid, tid, l);
    gbar(cnt + 16 * bi++, tid, bid);

    ph_aff1(p, SM, bid, tid, l);
    gbar(cnt + 16 * bi++, tid, bid);

    if (bid < 128) ph_ff2(p, SM, bid, tid, l);
    gbar(cnt + 16 * bi++, tid, bid);
  }

  if (bid < 32) ph_fc(p, SM, bid, tid);
}

extern "C" void kernel_launch(void* const* d_in, const int* in_sizes, int n_in,
                              void* d_out, int out_size, void* d_ws, size_t ws_size,
                              hipStream_t stream) {
  ushort* ws = (ushort*)d_ws;
  P p;
  p.x    = (const float*)d_in[0];
  p.c1w  = (const float*)d_in[1];
  p.c1b  = (const float*)d_in[2];
  p.c2w  = (const float*)d_in[3];
  p.c2b  = (const float*)d_in[4];
  p.lnfg = (const float*)d_in[5];
  p.lnfb = (const float*)d_in[6];
  p.tw   = (const float*)d_in[7];
  p.tb   = (const float*)d_in[8];
  p.sw   = (const float*)d_in[9];
  p.sb   = (const float*)d_in[10];
  p.aiw  = (const float*)d_in[11];
  p.aib  = (const float*)d_in[12];
  p.aow  = (const float*)d_in[13];
  p.aobb = (const float*)d_in[14];
  p.l1g  = (const float*)d_in[15];
  p.l1b  = (const float*)d_in[16];
  p.f1w  = (const float*)d_in[17];
  p.f1b  = (const float*)d_in[18];
  p.f2w  = (const float*)d_in[19];
  p.f2b  = (const float*)d_in[20];
  p.l2g  = (const float*)d_in[21];
  p.l2b  = (const float*)d_in[22];
  p.fcw  = (const float*)d_in[23];
  p.fcb  = (const float*)d_in[24];
  p.ws   = ws;
  p.out  = (float*)d_out;
  p.c2o  = (float*)(ws + O_C2O);
  p.g0   = (float*)(ws + O_G0);
  p.g1   = (float*)(ws + O_G1);
  p.pend = (float*)(ws + O_PEND);
  p.qkvo = ws + O_QKV;
  p.ffbo = ws + O_FFB;

  // zero the 15 tree barriers (16 uints each)
  hipMemsetAsync((char*)d_ws + (size_t)O_BAR * 2, 0, 1024, stream);
  mega<<<NBLK, 256, 0, stream>>>(p);
}

// Round 21
// 149.095 us; speedup vs baseline: 1.6775x; 1.6775x over previous
//
#include <hip/hip_runtime.h>
#include <math.h>

typedef __attribute__((ext_vector_type(8))) short short8;
typedef __attribute__((ext_vector_type(4))) short short4v;
typedef __attribute__((ext_vector_type(4))) float f32x4;
typedef unsigned short ushort;
typedef unsigned int uint;
typedef unsigned long long u64;

#define MFMA16(a, b, c) __builtin_amdgcn_mfma_f32_16x16x32_bf16(a, b, c, 0, 0, 0)

__device__ __forceinline__ ushort f2bf(float f) {
  uint u = __float_as_uint(f);
  u = (u + 0x7FFFu + ((u >> 16) & 1u)) >> 16;
  return (ushort)u;
}
__device__ __forceinline__ int swz(int idx, int sh) {
  return idx ^ (((idx >> sh) & 7) << 3);
}
__device__ __forceinline__ float wsum(float v) {
#pragma unroll
  for (int off = 32; off > 0; off >>= 1) v += __shfl_xor(v, off, 64);
  return v;
}
__device__ __forceinline__ void gload16(short8& dst, const ushort* g) {
  u64 ga = (u64)g;
  asm volatile("global_load_dwordx4 %0, %1, off" : "=v"(dst) : "v"(ga));
}
__device__ __forceinline__ void vmw(int n) {
  if (n >= 7) asm volatile("s_waitcnt vmcnt(7)" ::: "memory");
  else if (n == 6) asm volatile("s_waitcnt vmcnt(6)" ::: "memory");
  else if (n == 5) asm volatile("s_waitcnt vmcnt(5)" ::: "memory");
  else if (n == 4) asm volatile("s_waitcnt vmcnt(4)" ::: "memory");
  else if (n == 3) asm volatile("s_waitcnt vmcnt(3)" ::: "memory");
  else if (n == 2) asm volatile("s_waitcnt vmcnt(2)" ::: "memory");
  else if (n == 1) asm volatile("s_waitcnt vmcnt(1)" ::: "memory");
  else asm volatile("s_waitcnt vmcnt(0)" ::: "memory");
}

// ---- weight stream layout (tile-major): chunk(1KB) = (tile, kc, ks) ------
#define S_CONV2 0
#define S_TREND 196608
#define S_SEASON 262144
#define S_QKV 327680
#define S_AOW 1114112
#define S_F1 1376256
#define S_F2 2424832
#define WTOT 3473408
// activation buffers (ushort offsets in d_ws)
#define O_C2O 3653632   // f32 [32][5120]
#define O_G0 3981312    // f32 [32][5120]
#define O_G1 4308992    // f32 [32][5120]
#define O_PEND 4636672  // f32 [32][5120]
#define O_QKV 4964352   // bf16 [32][15360]
#define O_FFB 5455872   // bf16 [32][20480]

template <int NCH>
__device__ __forceinline__ void dec2(int idx, int& row, int& k) {
  int pos = idx & 511, lane = pos >> 3, j = pos & 7;
  int kg = lane >> 4, col = lane & 15;
  int chunk = idx >> 9;
  int tile = chunk / (NCH * 4), r = chunk - tile * (NCH * 4);
  int kc = r >> 2, ks = r & 3;
  row = tile * 16 + col;
  k = kc * 128 + ks * 32 + kg * 8 + j;
}

__global__ void k_cvt(const float* __restrict__ c2w, const float* __restrict__ tw,
                      const float* __restrict__ sw, const float* __restrict__ aiw,
                      const float* __restrict__ aow, const float* __restrict__ f1w,
                      const float* __restrict__ f2w, ushort* __restrict__ ws) {
  for (int i = blockIdx.x * blockDim.x + threadIdx.x; i < WTOT;
       i += gridDim.x * blockDim.x) {
    float v; int row, k;
    if (i < S_TREND) {
      dec2<6>(i, row, k);
      int t = k >> 8, e = k & 255;
      v = c2w[row * 768 + e * 3 + t];
    } else if (i < S_SEASON) { dec2<2>(i - S_TREND, row, k); v = tw[row * 256 + k]; }
    else if (i < S_QKV) { dec2<2>(i - S_SEASON, row, k); v = sw[row * 256 + k]; }
    else if (i < S_AOW) {
      int r = i - S_QKV; int l = r / 196608; r -= l * 196608;
      dec2<2>(r, row, k); v = aiw[(size_t)l * 196608 + row * 256 + k];
    } else if (i < S_F1) {
      int r = i - S_AOW; int l = r >> 16; r &= 65535;
      dec2<2>(r, row, k); v = aow[l * 65536 + row * 256 + k];
    } else if (i < S_F2) {
      int r = i - S_F1; int l = r >> 18; r &= 262143;
      dec2<2>(r, row, k); v = f1w[l * 262144 + row * 256 + k];
    } else {
      int r = i - S_F2; int l = r >> 18; r &= 262143;
      dec2<8>(r, row, k); v = f2w[l * 262144 + row * 1024 + k];
    }
    ws[i] = f2bf(v);
  }
}

// ---- generic ring GEMM core: wave streams MY consecutive tiles ----------
template <int NCH, int MY, int ASH>
__device__ __forceinline__ void ring_gemm(const ushort* __restrict__ A, int lda,
                                          const ushort* __restrict__ ws0,
                                          int lane, f32x4 (&acc)[MY][2]) {
  constexpr int C = MY * NCH * 4;
  constexpr int R = (C < 8) ? C : 8;
  const int col = lane & 15, kg = lane >> 4;
  const int r1c = (16 + col > 19) ? 19 : (16 + col);
  short8 rg[R];
#pragma unroll
  for (int r = 0; r < R; ++r) gload16(rg[r], ws0 + r * 512);
  short8 af0[4], af1[4];
#pragma unroll
  for (int c = 0; c < C; ++c) {
    const int i = c / (NCH * 4), r = c - i * (NCH * 4);
    const int kc = r >> 2, ks = r & 3;
    if (ks == 0) {
#pragma unroll
      for (int s = 0; s < 4; ++s) {
        const int k0 = kc * 128 + s * 32 + kg * 8;
        af0[s] = *(const short8*)(A + swz(col * lda + k0, ASH));
        af1[s] = *(const short8*)(A + swz(r1c * lda + k0, ASH));
      }
    }
    int allow = C - 1 - c; if (allow > R - 1) allow = R - 1;
    vmw(allow);
    __builtin_amdgcn_sched_barrier(0);
    acc[i][0] = MFMA16(af0[ks], rg[c % R], acc[i][0]);
    acc[i][1] = MFMA16(af1[ks], rg[c % R], acc[i][1]);
    if (c + R < C) gload16(rg[c % R], ws0 + (c + R) * 512);
  }
}

// ---- A staging helpers (256 threads) ------------------------------------
__device__ __forceinline__ void stage_b16(const ushort* __restrict__ g, ushort* hb,
                                          int n, int sh, int tid) {
  for (int i = tid * 8; i < n; i += 2048) {
    short8 v = *(const short8*)(g + i);
    *(short8*)(hb + swz(i, sh)) = v;
  }
}
__device__ __forceinline__ void stage_f32(const float* __restrict__ g, ushort* hb, int tid) {
  for (int i = tid * 8; i < 5120; i += 2048) {
    float4 a = *(const float4*)(g + i);
    float4 b = *(const float4*)(g + i + 4);
    short8 t;
    t[0] = f2bf(a.x); t[1] = f2bf(a.y); t[2] = f2bf(a.z); t[3] = f2bf(a.w);
    t[4] = f2bf(b.x); t[5] = f2bf(b.y); t[6] = f2bf(b.z); t[7] = f2bf(b.w);
    *(short8*)(hb + swz(i, 8)) = t;
  }
}
// LN(g1 [+pend]) -> hb bf16 swz8 ; optional fp32 writeback gout / LDS copy
__device__ __forceinline__ void stage_ln(const float* __restrict__ g1,
                                         const float* __restrict__ pend,
                                         const float* __restrict__ gam,
                                         const float* __restrict__ bet,
                                         ushort* hb, float* __restrict__ gout,
                                         float* f32lds, int tid) {
  const int lane = tid & 63, w = tid >> 6, d0 = lane * 4;
  for (int r = w; r < 20; r += 4) {
    float4 a = *(const float4*)(g1 + r * 256 + d0);
    if (pend) {
      float4 p = *(const float4*)(pend + r * 256 + d0);
      a.x += p.x; a.y += p.y; a.z += p.z; a.w += p.w;
    }
    float m = wsum(a.x + a.y + a.z + a.w) * (1.f / 256.f);
    float c0 = a.x - m, c1 = a.y - m, c2 = a.z - m, c3 = a.w - m;
    float var = wsum(c0 * c0 + c1 * c1 + c2 * c2 + c3 * c3) * (1.f / 256.f);
    float inv = rsqrtf(var + 1e-5f);
    float o0 = c0 * inv * gam[d0] + bet[d0];
    float o1 = c1 * inv * gam[d0 + 1] + bet[d0 + 1];
    float o2 = c2 * inv * gam[d0 + 2] + bet[d0 + 2];
    float o3 = c3 * inv * gam[d0 + 3] + bet[d0 + 3];
    short4v t; t[0] = f2bf(o0); t[1] = f2bf(o1); t[2] = f2bf(o2); t[3] = f2bf(o3);
    *(short4v*)(hb + swz(r * 256 + d0, 8)) = t;
    if (gout) { float4 o = {o0, o1, o2, o3}; *(float4*)(gout + r * 256 + d0) = o; }
    if (f32lds) { float4 o = {o0, o1, o2, o3}; *(float4*)(f32lds + r * 256 + d0) = o; }
  }
}

// ---- phase kernels -------------------------------------------------------
// conv1 fused into conv2: each block recomputes conv1 (cheap) in LDS.
__global__ __launch_bounds__(256, 2) void k_conv12(
    const float* __restrict__ x, const float* __restrict__ c1w,
    const float* __restrict__ c1b, const ushort* __restrict__ wst,
    const float* __restrict__ c2b, float* __restrict__ c2o) {
  __shared__ float xs[24][16];
  __shared__ __align__(16) ushort c1u[5632];
  const int tid = threadIdx.x, lane = tid & 63, wv = tid >> 6;
  const int b = blockIdx.x >> 2, slice = blockIdx.x & 3;
  const int col = lane & 15, kg = lane >> 4;
  for (int i = tid; i < 24 * 16; i += 256) {
    int r = i >> 4, c = i & 15;
    xs[r][c] = (r < 23) ? x[((size_t)b * 4000 + 3977 + r) * 16 + c] : 0.f;
  }
  __syncthreads();
  {
    const int d = tid;
    const float* wr = c1w + d * 48;
    float acc[21];
    const float bv = c1b[d];
#pragma unroll
    for (int r = 0; r < 21; ++r) acc[r] = bv;
    for (int c = 0; c < 16; ++c) {
      float xv[23];
#pragma unroll
      for (int i = 0; i < 23; ++i) xv[i] = xs[i + 1][c];
      float w0 = wr[c * 3], w1 = wr[c * 3 + 1], w2 = wr[c * 3 + 2];
#pragma unroll
      for (int r = 0; r < 21; ++r)
        acc[r] += xv[r] * w0 + xv[r + 1] * w1 + xv[r + 2] * w2;
    }
#pragma unroll
    for (int r = 0; r < 21; ++r)
      c1u[swz(r * 256 + d, 8)] = f2bf(fmaxf(acc[r], 0.f));
    c1u[swz(21 * 256 + d, 8)] = 0;
  }
  const int tile = slice * 4 + wv, og = tile * 16 + col;
  float bv2 = c2b[og];
  __syncthreads();
  asm volatile("s_waitcnt vmcnt(0)" ::: "memory");
  f32x4 acc2[1][2];
  acc2[0][0] = {bv2, bv2, bv2, bv2}; acc2[0][1] = {bv2, bv2, bv2, bv2};
  ring_gemm<6, 1, 8>(c1u, 256, wst + tile * 12288 + lane * 8, lane, acc2);
  float* ob = c2o + b * 5120;
#pragma unroll
  for (int mt = 0; mt < 2; ++mt)
#pragma unroll
    for (int j = 0; j < 4; ++j) {
      int row = mt * 16 + kg * 4 + j;
      if (row < 20) ob[row * 256 + og] = fmaxf(acc2[0][mt][j], 0.f);
    }
}

__global__ __launch_bounds__(256, 2) void k_tresea(
    const float* __restrict__ c2o, const ushort* __restrict__ wtr,
    const ushort* __restrict__ wse, const float* __restrict__ lnfg,
    const float* __restrict__ lnfb, const float* __restrict__ tb,
    const float* __restrict__ sb, float* __restrict__ g0) {
  __shared__ __align__(16) ushort hb[5120];
  __shared__ float hf[5120];
  const int tid = threadIdx.x, lane = tid & 63, wv = tid >> 6;
  const int b = blockIdx.x >> 2, slice = blockIdx.x & 3;
  const int col = lane & 15, kg = lane >> 4;
  stage_ln(c2o + b * 5120, nullptr, lnfg, lnfb, hb, nullptr, hf, tid);
  const int tile = slice * 4 + wv, og = tile * 16 + col;
  float bt = tb[og], bs = sb[og];
  __syncthreads();
  asm volatile("s_waitcnt vmcnt(0)" ::: "memory");
  f32x4 at[1][2], as_[1][2];
  at[0][0] = {bt, bt, bt, bt}; at[0][1] = {bt, bt, bt, bt};
  as_[0][0] = {bs, bs, bs, bs}; as_[0][1] = {bs, bs, bs, bs};
  ring_gemm<2, 1, 8>(hb, 256, wtr + tile * 4096 + lane * 8, lane, at);
  ring_gemm<2, 1, 8>(hb, 256, wse + tile * 4096 + lane * 8, lane, as_);
  float* ob = g0 + b * 5120;
#pragma unroll
  for (int mt = 0; mt < 2; ++mt)
#pragma unroll
    for (int j = 0; j < 4; ++j) {
      int row = mt * 16 + kg * 4 + j;
      if (row < 20)
        ob[row * 256 + og] = hf[row * 256 + og] + at[0][mt][j] + sinf(as_[0][mt][j]);
    }
}

// qkv projection; fuse_ln: A = LN2(g_in + pend) (slice0 writes gout fp32)
__global__ __launch_bounds__(256, 2) void k_qkv(
    const float* __restrict__ gin, const float* __restrict__ pend,
    const float* __restrict__ lng, const float* __restrict__ lnb, int fuse_ln,
    float* __restrict__ gout, const ushort* __restrict__ wst,
    const float* __restrict__ bias, ushort* __restrict__ qkvo) {
  __shared__ __align__(16) ushort hb[5120];
  const int tid = threadIdx.x, lane = tid & 63, wv = tid >> 6;
  const int b = blockIdx.x / 12, slice = blockIdx.x % 12;
  const int col = lane & 15, kg = lane >> 4;
  if (fuse_ln)
    stage_ln(gin + b * 5120, pend + b * 5120, lng, lnb, hb,
             (slice == 0) ? (gout + b * 5120) : nullptr, nullptr, tid);
  else
    stage_f32(gin + b * 5120, hb, tid);
  const int tile = slice * 4 + wv, og = tile * 16 + col;
  float bv = bias[og];
  __syncthreads();
  asm volatile("s_waitcnt vmcnt(0)" ::: "memory");
  f32x4 acc[1][2];
  acc[0][0] = {bv, bv, bv, bv}; acc[0][1] = {bv, bv, bv, bv};
  ring_gemm<2, 1, 8>(hb, 256, wst + tile * 4096 + lane * 8, lane, acc);
  ushort* ob = qkvo + b * 15360;
#pragma unroll
  for (int mt = 0; mt < 2; ++mt)
#pragma unroll
    for (int j = 0; j < 4; ++j) {
      int row = mt * 16 + kg * 4 + j;
      if (row < 20) ob[row * 768 + og] = f2bf(acc[0][mt][j]);
    }
}

// fused: attention (redundant per slice) + FULL out-proj + LN1 + ff1 slice
__global__ __launch_bounds__(256, 1) void k_aff1(
    const ushort* __restrict__ qkvo, const ushort* __restrict__ waow,
    const float* __restrict__ aobb, const float* __restrict__ g0,
    const float* __restrict__ l1g, const float* __restrict__ l1b,
    float* __restrict__ g1, const ushort* __restrict__ wf1,
    const float* __restrict__ f1b, ushort* __restrict__ ffbo) {
  __shared__ __align__(16) ushort qb[15360];  // proj f32 overlays after QK^T
  __shared__ __align__(16) ushort vT[8192];
  __shared__ __align__(16) ushort Pb[5120];
  __shared__ __align__(16) ushort aob[5120];
  __shared__ float sc[3200];
  __shared__ __align__(16) ushort hb[5120];
  float* proj = (float*)qb;  // 20480B <= 30720B, qb dead after QK^T
  const int tid = threadIdx.x, lane = tid & 63, wv = tid >> 6;
  const int b = blockIdx.x >> 3, slice = blockIdx.x & 7;
  const int col = lane & 15, kg = lane >> 4;
  const int r1c = (16 + col > 19) ? 19 : (16 + col);

  stage_b16(qkvo + b * 15360, qb, 15360, 8, tid);
  __syncthreads();
  for (int i = tid; i < 8192; i += 256) {
    int hh = i >> 10, rem = i & 1023, dh = rem >> 5, tk = rem & 31;
    ushort v = (tk < 20) ? qb[swz(tk * 768 + 512 + hh * 32 + dh, 8)] : (ushort)0;
    vT[swz(i, 5)] = v;
  }
  __syncthreads();
  for (int hh = wv; hh < 8; hh += 4) {
    short8 aq[2], bk[2];
    aq[0] = *(const short8*)(qb + swz(col * 768 + hh * 32 + kg * 8, 8));
    aq[1] = *(const short8*)(qb + swz(r1c * 768 + hh * 32 + kg * 8, 8));
    bk[0] = *(const short8*)(qb + swz(col * 768 + 256 + hh * 32 + kg * 8, 8));
    bk[1] = *(const short8*)(qb + swz(r1c * 768 + 256 + hh * 32 + kg * 8, 8));
    f32x4 d[2][2];
#pragma unroll
    for (int mt = 0; mt < 2; ++mt)
#pragma unroll
      for (int nt = 0; nt < 2; ++nt) {
        d[mt][nt] = {0.f, 0.f, 0.f, 0.f};
        d[mt][nt] = MFMA16(aq[mt], bk[nt], d[mt][nt]);
      }
#pragma unroll
    for (int mt = 0; mt < 2; ++mt)
#pragma unroll
      for (int nt = 0; nt < 2; ++nt)
#pragma unroll
        for (int j = 0; j < 4; ++j) {
          int row = mt * 16 + kg * 4 + j, kj = nt * 16 + col;
          if (row < 20 && kj < 20)
            sc[hh * 400 + row * 20 + kj] = d[mt][nt][j] * 0.17677669529663687f;
        }
  }
  __syncthreads();
  if (tid < 160) {
    const int hh = tid / 20, q = tid - hh * 20;
    const float* row = sc + hh * 400 + q * 20;
    float m = row[0];
#pragma unroll
    for (int j = 1; j < 20; ++j) m = fmaxf(m, row[j]);
    float e[20], s = 0.f;
#pragma unroll
    for (int j = 0; j < 20; ++j) { e[j] = __expf(row[j] - m); s += e[j]; }
    float inv = 1.f / s;
#pragma unroll
    for (int j = 0; j < 20; ++j) Pb[swz(hh * 640 + q * 32 + j, 5)] = f2bf(e[j] * inv);
#pragma unroll
    for (int j = 20; j < 32; ++j) Pb[swz(hh * 640 + q * 32 + j, 5)] = 0;
  }
  __syncthreads();
  for (int hh = wv; hh < 8; hh += 4) {
    short8 ap[2], bvv[2];
    ap[0] = *(const short8*)(Pb + swz(hh * 640 + col * 32 + kg * 8, 5));
    ap[1] = *(const short8*)(Pb + swz(hh * 640 + r1c * 32 + kg * 8, 5));
    bvv[0] = *(const short8*)(vT + swz(hh * 1024 + col * 32 + kg * 8, 5));
    bvv[1] = *(const short8*)(vT + swz(hh * 1024 + (16 + col) * 32 + kg * 8, 5));
    f32x4 d[2][2];
#pragma unroll
    for (int mt = 0; mt < 2; ++mt)
#pragma unroll
      for (int nt = 0; nt < 2; ++nt) {
        d[mt][nt] = {0.f, 0.f, 0.f, 0.f};
        d[mt][nt] = MFMA16(ap[mt], bvv[nt], d[mt][nt]);
      }
#pragma unroll
    for (int mt = 0; mt < 2; ++mt)
#pragma unroll
      for (int nt = 0; nt < 2; ++nt)
#pragma unroll
        for (int j = 0; j < 4; ++j) {
          int row = mt * 16 + kg * 4 + j, dc = nt * 16 + col;
          if (row < 20) aob[swz(row * 256 + hh * 32 + dc, 8)] = f2bf(d[mt][nt][j]);
        }
  }
  __syncthreads();

  // FULL out-projection: wave wv computes tiles wv*4 .. wv*4+3 -> proj f32
  {
    float bo[4];
#pragma unroll
    for (int i = 0; i < 4; ++i) bo[i] = aobb[(wv * 4 + i) * 16 + col];
    asm volatile("s_waitcnt vmcnt(0)" ::: "memory");
    f32x4 acc[4][2];
#pragma unroll
    for (int i = 0; i < 4; ++i) {
      acc[i][0] = {bo[i], bo[i], bo[i], bo[i]};
      acc[i][1] = {bo[i], bo[i], bo[i], bo[i]};
    }
    ring_gemm<2, 4, 8>(aob, 256, waow + (wv * 4) * 4096 + lane * 8, lane, acc);
#pragma unroll
    for (int i = 0; i < 4; ++i) {
      const int og = (wv * 4 + i) * 16 + col;
#pragma unroll
      for (int mt = 0; mt < 2; ++mt)
#pragma unroll
        for (int j = 0; j < 4; ++j) {
          int row = mt * 16 + kg * 4 + j;
          if (row < 20) proj[row * 256 + og] = acc[i][mt][j];
        }
    }
  }
  __syncthreads();

  // LN1(g0 + proj) -> hb bf16 (slice0 writes g1 fp32)
  {
    const int d0 = lane * 4;
    for (int r = wv; r < 20; r += 4) {
      float4 a = *(const float4*)(g0 + b * 5120 + r * 256 + d0);
      a.x += proj[r * 256 + d0];
      a.y += proj[r * 256 + d0 + 1];
      a.z += proj[r * 256 + d0 + 2];
      a.w += proj[r * 256 + d0 + 3];
      float m = wsum(a.x + a.y + a.z + a.w) * (1.f / 256.f);
      float c0 = a.x - m, c1 = a.y - m, c2 = a.z - m, c3 = a.w - m;
      float var = wsum(c0 * c0 + c1 * c1 + c2 * c2 + c3 * c3) * (1.f / 256.f);
      float inv = rsqrtf(var + 1e-5f);
      float o0 = c0 * inv * l1g[d0] + l1b[d0];
      float o1 = c1 * inv * l1g[d0 + 1] + l1b[d0 + 1];
      float o2 = c2 * inv * l1g[d0 + 2] + l1b[d0 + 2];
      float o3 = c3 * inv * l1g[d0 + 3] + l1b[d0 + 3];
      short4v t; t[0] = f2bf(o0); t[1] = f2bf(o1); t[2] = f2bf(o2); t[3] = f2bf(o3);
      *(short4v*)(hb + swz(r * 256 + d0, 8)) = t;
      if (slice == 0) {
        float4 o = {o0, o1, o2, o3};
        *(float4*)(g1 + b * 5120 + r * 256 + d0) = o;
      }
    }
  }
  __syncthreads();

  // ff1 slice: wave does tiles t0 = slice*8 + wv*2, +1 (relu, bf16 out)
  {
    const int t0 = slice * 8 + wv * 2;
    float bf0 = f1b[t0 * 16 + col], bf1 = f1b[(t0 + 1) * 16 + col];
    asm volatile("s_waitcnt vmcnt(0)" ::: "memory");
    f32x4 acc[2][2];
    acc[0][0] = {bf0, bf0, bf0, bf0}; acc[0][1] = {bf0, bf0, bf0, bf0};
    acc[1][0] = {bf1, bf1, bf1, bf1}; acc[1][1] = {bf1, bf1, bf1, bf1};
    ring_gemm<2, 2, 8>(hb, 256, wf1 + t0 * 4096 + lane * 8, lane, acc);
    ushort* ob = ffbo + b * 20480;
#pragma unroll
    for (int i = 0; i < 2; ++i) {
      const int og = (t0 + i) * 16 + col;
#pragma unroll
      for (int mt = 0; mt < 2; ++mt)
#pragma unroll
        for (int j = 0; j < 4; ++j) {
          int row = mt * 16 + kg * 4 + j;
          if (row < 20) ob[row * 1024 + og] = f2bf(fmaxf(acc[i][mt][j], 0.f));
        }
    }
  }
}

__global__ __launch_bounds__(256, 2) void k_ff2(const ushort* __restrict__ ffbo,
                                                const ushort* __restrict__ wst,
                                                const float* __restrict__ bias,
                                                float* __restrict__ pend) {
  __shared__ __align__(16) ushort hb[20480];
  const int tid = threadIdx.x, lane = tid & 63, wv = tid >> 6;
  const int b = blockIdx.x >> 2, slice = blockIdx.x & 3;
  const int col = lane & 15, kg = lane >> 4;
  stage_b16(ffbo + b * 20480, hb, 20480, 10, tid);
  const int tile = slice * 4 + wv, og = tile * 16 + col;
  float bv = bias[og];
  __syncthreads();
  asm volatile("s_waitcnt vmcnt(0)" ::: "memory");
  f32x4 acc[1][2];
  acc[0][0] = {bv, bv, bv, bv}; acc[0][1] = {bv, bv, bv, bv};
  ring_gemm<8, 1, 10>(hb, 1024, wst + tile * 16384 + lane * 8, lane, acc);
  float* ob = pend + b * 5120;
#pragma unroll
  for (int mt = 0; mt < 2; ++mt)
#pragma unroll
    for (int j = 0; j < 4; ++j) {
      int row = mt * 16 + kg * 4 + j;
      if (row < 20) ob[row * 256 + og] = acc[0][mt][j];
    }
}

__global__ __launch_bounds__(256) void k_fc(
    const float* __restrict__ g1, const float* __restrict__ pend,
    const float* __restrict__ lng, const float* __restrict__ lnb,
    const float* __restrict__ fcw, const float* __restrict__ fcb,
    float* __restrict__ out) {
  __shared__ float hn[256];
  const int tid = threadIdx.x, b = blockIdx.x;
  if (tid < 64) {
    const int d0 = tid * 4;
    float4 a = *(const float4*)(g1 + b * 5120 + 19 * 256 + d0);
    float4 p = *(const float4*)(pend + b * 5120 + 19 * 256 + d0);
    a.x += p.x; a.y += p.y; a.z += p.z; a.w += p.w;
    float m = wsum(a.x + a.y + a.z + a.w) * (1.f / 256.f);
    float c0 = a.x - m, c1 = a.y - m, c2 = a.z - m, c3 = a.w - m;
    float var = wsum(c0 * c0 + c1 * c1 + c2 * c2 + c3 * c3) * (1.f / 256.f);
    float inv = rsqrtf(var + 1e-5f);
    hn[d0] = c0 * inv * lng[d0] + lnb[d0];
    hn[d0 + 1] = c1 * inv * lng[d0 + 1] + lnb[d0 + 1];
    hn[d0 + 2] = c2 * inv * lng[d0 + 2] + lnb[d0 + 2];
    hn[d0 + 3] = c3 * inv * lng[d0 + 3] + lnb[d0 + 3];
  }
  __syncthreads();
  const int g = tid >> 4, t = tid & 15;
  float s = 0.f;
#pragma unroll
  for (int j = 0; j < 16; ++j) {
    int k = t * 16 + j;
    s += hn[k] * fcw[g * 256 + k];
  }
#pragma unroll
  for (int off = 1; off < 16; off <<= 1) s += __shfl_xor(s, off, 64);
  if (t == 0) out[b * 16 + g] = s + fcb[g];
}

extern "C" void kernel_launch(void* const* d_in, const int* in_sizes, int n_in,
                              void* d_out, int out_size, void* d_ws, size_t ws_size,
                              hipStream_t stream) {
  const float* x    = (const float*)d_in[0];
  const float* c1w  = (const float*)d_in[1];
  const float* c1b  = (const float*)d_in[2];
  const float* c2w  = (const float*)d_in[3];
  const float* c2b  = (const float*)d_in[4];
  const float* lnfg = (const float*)d_in[5];
  const float* lnfb = (const float*)d_in[6];
  const float* tw   = (const float*)d_in[7];
  const float* tb   = (const float*)d_in[8];
  const float* sw   = (const float*)d_in[9];
  const float* sb   = (const float*)d_in[10];
  const float* aiw  = (const float*)d_in[11];
  const float* aib  = (const float*)d_in[12];
  const float* aow  = (const float*)d_in[13];
  const float* aobb = (const float*)d_in[14];
  const float* l1g  = (const float*)d_in[15];
  const float* l1b  = (const float*)d_in[16];
  const float* f1w  = (const float*)d_in[17];
  const float* f1b  = (const float*)d_in[18];
  const float* f2w  = (const float*)d_in[19];
  const float* f2b  = (const float*)d_in[20];
  const float* l2g  = (const float*)d_in[21];
  const float* l2b  = (const float*)d_in[22];
  const float* fcw  = (const float*)d_in[23];
  const float* fcb  = (const float*)d_in[24];
  float* out = (float*)d_out;
  ushort* ws = (ushort*)d_ws;

  float* c2o   = (float*)(ws + O_C2O);
  float* g0    = (float*)(ws + O_G0);
  float* g1    = (float*)(ws + O_G1);
  float* pend  = (float*)(ws + O_PEND);
  ushort* qkvo = ws + O_QKV;
  ushort* ffbo = ws + O_FFB;

  k_cvt<<<2048, 256, 0, stream>>>(c2w, tw, sw, aiw, aow, f1w, f2w, ws);
  k_conv12<<<128, 256, 0, stream>>>(x, c1w, c1b, ws + S_CONV2, c2b, c2o);
  k_tresea<<<128, 256, 0, stream>>>(c2o, ws + S_TREND, ws + S_SEASON, lnfg,
                                    lnfb, tb, sb, g0);
  for (int l = 0; l < 4; ++l) {
    k_qkv<<<384, 256, 0, stream>>>(
        l == 0 ? g0 : g1, pend, l ? l2g + (l - 1) * 256 : nullptr,
        l ? l2b + (l - 1) * 256 : nullptr, l ? 1 : 0, g0,
        ws + S_QKV + l * 196608, aib + l * 768, qkvo);
    k_aff1<<<256, 256, 0, stream>>>(qkvo, ws + S_AOW + l * 65536,
                                    aobb + l * 256, g0, l1g + l * 256,
                                    l1b + l * 256, g1, ws + S_F1 + l * 262144,
                                    f1b + l * 1024, ffbo);
    k_ff2<<<128, 256, 0, stream>>>(ffbo, ws + S_F2 + l * 262144, f2b + l * 256,
                                   pend);
  }
  k_fc<<<32, 256, 0, stream>>>(g1, pend, l2g + 3 * 256, l2b + 3 * 256, fcw,
                               fcb, out);
}